// Round 5
// baseline (334.142 us; speedup 1.0000x reference)
//
#include <hip/hip_runtime.h>
#include <cstdint>
#include <cstddef>
#include <utility>

#define PI_F 3.14159265358979323846f

typedef __attribute__((ext_vector_type(8))) _Float16 half8;
typedef __attribute__((ext_vector_type(4))) float f32x4;

struct U4 { unsigned int w[4]; };

static __device__ __forceinline__ unsigned int packhalf2(float c, float s) {
  _Float16 hc = (_Float16)c, hs = (_Float16)s;
  unsigned short uc = __builtin_bit_cast(unsigned short, hc);
  unsigned short us = __builtin_bit_cast(unsigned short, hs);
  return (unsigned int)uc | ((unsigned int)us << 16);
}

static __device__ __forceinline__ void load16_lds(const void* g, void* l) {
  __builtin_amdgcn_global_load_lds(
      (const __attribute__((address_space(1))) unsigned int*)g,
      (__attribute__((address_space(3))) unsigned int*)l, 16, 0, 0);
}

// ---------------------------------------------------------------------------
// K1: MLP for all 2B samples -> hz[sample][16] = {h[0..7], z[0..6], 0}.
// Block 0 thread 0 also zero-inits scalars + out (replaces 2 memset dispatches).
// ---------------------------------------------------------------------------
__global__ __launch_bounds__(256) void k_mlp(
    const float* __restrict__ x1, const float* __restrict__ x0,
    const float* __restrict__ W1, const float* __restrict__ b1,
    const float* __restrict__ W2, const float* __restrict__ b2,
    const float* __restrict__ W3, const float* __restrict__ b3,
    float* __restrict__ hz, int B, float* __restrict__ scalars,
    float* __restrict__ out) {
  int s = blockIdx.x * blockDim.x + threadIdx.x;
  if (blockIdx.x == 0 && threadIdx.x == 0) {
    scalars[0] = 0.f;
    scalars[1] = 0.f;
    out[0] = 0.f;
  }
  if (s >= 2 * B) return;
  const float* xp = (s < B) ? (x1 + (size_t)s * 8) : (x0 + (size_t)(s - B) * 8);
  float x[8];
#pragma unroll
  for (int k = 0; k < 8; k++) x[k] = xp[k];
  float a1[10];
#pragma unroll
  for (int o = 0; o < 10; o++) {
    float v = b1[o];
#pragma unroll
    for (int k = 0; k < 8; k++) v = fmaf(W1[o * 8 + k], x[k], v);
    a1[o] = fmaxf(v, 0.f);
  }
  float a2[10];
#pragma unroll
  for (int o = 0; o < 10; o++) {
    float v = b2[o];
#pragma unroll
    for (int k = 0; k < 10; k++) v = fmaf(W2[o * 10 + k], a1[k], v);
    a2[o] = fmaxf(v, 0.f);
  }
  float h[8];
#pragma unroll
  for (int o = 0; o < 8; o++) {
    float v = b3[o];
#pragma unroll
    for (int k = 0; k < 10; k++) v = fmaf(W3[o * 10 + k], a2[k], v);
    h[o] = v;
  }
  float outv[16];
#pragma unroll
  for (int k = 0; k < 8; k++) outv[k] = h[k];
#pragma unroll
  for (int k = 0; k < 7; k++) outv[8 + k] = (PI_F - h[k]) * (PI_F - h[k + 1]);
  outv[15] = 0.f;
  float4* dst = (float4*)(hz + (size_t)s * 16);
#pragma unroll
  for (int q = 0; q < 4; q++) dst[q] = ((float4*)outv)[q];
}

// ---------------------------------------------------------------------------
// K2: generate fp16 (cos,sin) pairs. A layout: [kb][256 rows][64 halfs],
// rows are 128B; within a row the 16B chunks are XOR-swizzled by (row&7):
//   physical_half(row, logical_half L) = L ^ ((row&7)<<3)
// so the GEMM stages linearly (global_load_lds) and reads conflict-free.
// ---------------------------------------------------------------------------
__global__ __launch_bounds__(256) void k_gen(const float* __restrict__ hz,
                                             _Float16* __restrict__ Ach) {
  __shared__ float hzl[32][16];
  int kb = blockIdx.x, t = threadIdx.x;
  if (t < 128) {
    int smp = t >> 2, q = t & 3;
    *(float4*)&hzl[smp][q * 4] =
        *(const float4*)(hz + (size_t)(kb * 32 + smp) * 16 + q * 4);
  }
  __syncthreads();
  int s = t & 31, oct = t >> 5;  // sample-in-block, basis octet
  float h[8], z[7];
#pragma unroll
  for (int k = 0; k < 8; k++) h[k] = hzl[s][k];
#pragma unroll
  for (int k = 0; k < 7; k++) z[k] = hzl[s][8 + k];
  _Float16* dst = Ach + (size_t)kb * 16384;
#pragma unroll
  for (int j = 0; j < 32; j++) {
    int i = j * 8 + oct;
    float sprev = ((i >> 7) & 1) ? -1.f : 1.f;  // wire 0 = MSB
    float phi = sprev * h[0];
#pragma unroll
    for (int k = 1; k < 8; k++) {
      float sk = ((i >> (7 - k)) & 1) ? -1.f : 1.f;
      phi += sk * h[k];
      phi += (sprev * sk) * z[k - 1];
      sprev = sk;
    }
    float sv, cv;
    sincosf(0.5f * phi, &sv, &cv);
    int halfoff = (2 * s) ^ ((i & 7) << 3);  // swizzled position in row
    *(unsigned int*)(dst + (size_t)i * 64 + halfoff) = packhalf2(cv, sv);
  }
}

// ---------------------------------------------------------------------------
// K3: triangular split-K MFMA GEMM -> per-slab partial tiles (no atomics).
// Templated on panel count: NP=1 for diagonal tiles (A==B, stage once,
// 32 KiB LDS), NP=2 for the off-diagonal tile (64 KiB LDS).
// diag:  grid (2, ZSLABS), bx=0 -> tile 0 (0,0), bx=1 -> tile 2 (128,128)
// off:   grid (1, ZSLABS), tile 1 (0,128)
// Partials P[(tile*ZSLABS+z)*2 + plane][128*128] f32.
// ---------------------------------------------------------------------------
#define ZSLABS 256

template <int NP>
__global__ __launch_bounds__(256) void k_gemm_t(const _Float16* __restrict__ A,
                                                float* __restrict__ P,
                                                int kbPer) {
  __shared__ _Float16 lds[2][NP][128][64];
  int bx = blockIdx.x, z = blockIdx.y;
  int mbase, nbase, tile;
  if (NP == 1) {
    mbase = bx * 128;
    nbase = bx * 128;
    tile = bx * 2;
  } else {
    mbase = 0;
    nbase = 128;
    tile = 1;
  }
  int t = threadIdx.x, wave = t >> 6, lane = t & 63;
  int wm = wave >> 1, wn = wave & 1;
  unsigned int reMask = (z < ZSLABS / 2) ? 0u : 0x80008000u;
  unsigned int imMask = (z < ZSLABS / 2) ? 0x80000000u : 0x00008000u;
  int kb0 = z * kbPer;

  auto stage = [&](int it, int buf) {
    size_t kb = (size_t)(kb0 + it);
    const char* gA = (const char*)A + kb * 32768 + (size_t)mbase * 128;
    char* lA = (char*)&lds[buf][0][0][0];
#pragma unroll
    for (int q = 0; q < 4; q++) {
      int woff = wave * 4096 + q * 1024;
      load16_lds(gA + woff + lane * 16, lA + woff);
    }
    if (NP == 2) {
      const char* gB = (const char*)A + kb * 32768 + (size_t)nbase * 128;
      char* lB = (char*)&lds[buf][NP - 1][0][0];
#pragma unroll
      for (int q = 0; q < 4; q++) {
        int woff = wave * 4096 + q * 1024;
        load16_lds(gB + woff + lane * 16, lB + woff);
      }
    }
  };

  f32x4 accR[4][4] = {};
  f32x4 accI[4][4] = {};
  stage(0, 0);
  for (int it = 0; it < kbPer; ++it) {
    __syncthreads();  // stage(it) complete; everyone done with buf[(it+1)&1]
    if (it + 1 < kbPer) stage(it + 1, (it + 1) & 1);
    int buf = it & 1;
#pragma unroll
    for (int kk = 0; kk < 2; kk++) {
      int cbase = kk * 4 + (lane >> 4);
      half8 af[4], bfr[4], bfi[4];
#pragma unroll
      for (int fm = 0; fm < 4; fm++) {
        int r = wm * 64 + fm * 16 + (lane & 15);
        af[fm] = *(const half8*)&lds[buf][0][r][(cbase ^ (r & 7)) << 3];
      }
#pragma unroll
      for (int fn = 0; fn < 4; fn++) {
        int r = wn * 64 + fn * 16 + (lane & 15);
        half8 bv = *(const half8*)&lds[buf][NP - 1][r][(cbase ^ (r & 7)) << 3];
        U4 u = __builtin_bit_cast(U4, bv), ur, ui;
#pragma unroll
        for (int q = 0; q < 4; q++) {
          unsigned int xv = u.w[q];
          ur.w[q] = xv ^ reMask;
          ui.w[q] = ((xv << 16) | (xv >> 16)) ^ imMask;
        }
        bfr[fn] = __builtin_bit_cast(half8, ur);
        bfi[fn] = __builtin_bit_cast(half8, ui);
      }
#pragma unroll
      for (int fm = 0; fm < 4; fm++)
#pragma unroll
        for (int fn = 0; fn < 4; fn++) {
          accR[fm][fn] = __builtin_amdgcn_mfma_f32_16x16x32_f16(
              af[fm], bfr[fn], accR[fm][fn], 0, 0, 0);
          accI[fm][fn] = __builtin_amdgcn_mfma_f32_16x16x32_f16(
              af[fm], bfi[fn], accI[fm][fn], 0, 0, 0);
        }
    }
  }
  float* PR = P + ((size_t)(tile * ZSLABS + z) * 2) * 16384;
  float* PI = PR + 16384;
  int r4 = (lane >> 4) * 4, cj = lane & 15;
#pragma unroll
  for (int fm = 0; fm < 4; fm++)
#pragma unroll
    for (int fn = 0; fn < 4; fn++)
#pragma unroll
      for (int r = 0; r < 4; r++) {
        int li = wm * 64 + fm * 16 + r4 + r;
        int lj = wn * 64 + fn * 16 + cj;
        PR[li * 128 + lj] = accR[fm][fn][r];
        PI[li * 128 + lj] = accI[fm][fn][r];
      }
}

// ---------------------------------------------------------------------------
// K4: reduce partials -> Hermitian A (scaled), accumulate ||A||_F^2.
// grid (128 rows, 3 tiles), 128 threads (one per col).
// ---------------------------------------------------------------------------
__global__ __launch_bounds__(128) void k_reduce(const float* __restrict__ P,
                                                float* __restrict__ AR,
                                                float* __restrict__ AI,
                                                float* __restrict__ sumsq,
                                                float scale) {
  int r = blockIdx.x, tile = blockIdx.y, c = threadIdx.x;
  float vR = 0.f, vI = 0.f;
  for (int zz = 0; zz < ZSLABS; zz++) {
    const float* base =
        P + ((size_t)(tile * ZSLABS + zz) * 2) * 16384 + r * 128 + c;
    vR += base[0];
    vI += base[16384];
  }
  vR *= scale;
  vI *= scale;
  int i = (tile == 2) ? 128 + r : r;
  int j = (tile == 0) ? c : 128 + c;
  float ss = 0.f;
  bool diagTile = (tile != 1);
  if (!diagTile || c > r) {
    AR[i * 256 + j] = vR;
    AR[j * 256 + i] = vR;
    AI[i * 256 + j] = vI;
    AI[j * 256 + i] = -vI;
    ss = 2.f * (vR * vR + vI * vI);
  } else if (c == r) {
    AR[i * 256 + j] = vR;
    AI[i * 256 + j] = 0.f;
    ss = vR * vR;
  }
#pragma unroll
  for (int o = 32; o > 0; o >>= 1) ss += __shfl_down(ss, o);
  __shared__ float w2[2];
  if ((c & 63) == 0) w2[c >> 6] = ss;
  __syncthreads();
  if (c == 0) atomicAdd(sumsq, w2[0] + w2[1]);
}

// K5: X = A / ||A||_F
__global__ __launch_bounds__(256) void k_scale(
    const float* __restrict__ AR, const float* __restrict__ AI,
    float* __restrict__ XR, float* __restrict__ XI,
    const float* __restrict__ sumsq) {
  int idx = blockIdx.x * 256 + threadIdx.x;
  float inva = 1.0f / sqrtf(sumsq[0]);
  XR[idx] = AR[idx] * inva;
  XI[idx] = AI[idx] * inva;
}

// ---------------------------------------------------------------------------
// Newton-Schulz complex matmuls, 16x16 tile per block, interleaved re/im LDS.
// ---------------------------------------------------------------------------
__global__ __launch_bounds__(256) void k_csq(
    const float* __restrict__ XR, const float* __restrict__ XI,
    float* __restrict__ YR, float* __restrict__ YI,
    float* __restrict__ sumsqY, int accumNorm) {
  __shared__ float rp[16][256][2];
  __shared__ float cpT[16][258][2];
  int t = threadIdx.x;
  int bi = blockIdx.x >> 4, bj = blockIdx.x & 15;
#pragma unroll
  for (int q = 0; q < 16; q++) {
    rp[q][t][0] = XR[(bi * 16 + q) * 256 + t];
    rp[q][t][1] = XI[(bi * 16 + q) * 256 + t];
  }
  {
    const float* r0 = XR + t * 256 + bj * 16;
    const float* i0 = XI + t * 256 + bj * 16;
#pragma unroll
    for (int c = 0; c < 16; c++) {
      cpT[c][t][0] = r0[c];
      cpT[c][t][1] = i0[c];
    }
  }
  __syncthreads();
  int tx = t & 15, ty = t >> 4;
  float sR = 0.f, sI = 0.f;
#pragma unroll 8
  for (int k = 0; k < 256; k++) {
    float xr = rp[ty][k][0], xi = rp[ty][k][1];
    float yr = cpT[tx][k][0], yi = cpT[tx][k][1];
    sR = fmaf(xr, yr, sR);
    sR = fmaf(-xi, yi, sR);
    sI = fmaf(xr, yi, sI);
    sI = fmaf(xi, yr, sI);
  }
  int i = bi * 16 + ty, j = bj * 16 + tx;
  YR[i * 256 + j] = sR;
  YI[i * 256 + j] = sI;
  if (accumNorm) {
    float v = sR * sR + sI * sI;
#pragma unroll
    for (int o = 32; o > 0; o >>= 1) v += __shfl_down(v, o);
    __shared__ float w4[4];
    if ((t & 63) == 0) w4[t >> 6] = v;
    __syncthreads();
    if (t == 0) atomicAdd(sumsqY, w4[0] + w4[1] + w4[2] + w4[3]);
  }
}

// Z = aC*X - bC*(X@Y).
// mode 0: first iter, 1.5-NS with spectral rescale folded in (clamps to (0,1])
// mode 1: x <- 2x - x^3      (doubling phase)
// mode 2: x <- 1.5x - 0.5x^3 (quadratic polish)
__global__ __launch_bounds__(256) void k_cupd(
    const float* __restrict__ XR, const float* __restrict__ XI,
    const float* __restrict__ YR, const float* __restrict__ YI,
    float* __restrict__ ZR, float* __restrict__ ZI,
    const float* __restrict__ sumsqY, int mode) {
  __shared__ float rp[16][256][2];
  __shared__ float cpT[16][258][2];
  int t = threadIdx.x;
  int bi = blockIdx.x >> 4, bj = blockIdx.x & 15;
#pragma unroll
  for (int q = 0; q < 16; q++) {
    rp[q][t][0] = XR[(bi * 16 + q) * 256 + t];
    rp[q][t][1] = XI[(bi * 16 + q) * 256 + t];
  }
  {
    const float* r0 = YR + t * 256 + bj * 16;
    const float* i0 = YI + t * 256 + bj * 16;
#pragma unroll
    for (int c = 0; c < 16; c++) {
      cpT[c][t][0] = r0[c];
      cpT[c][t][1] = i0[c];
    }
  }
  __syncthreads();
  int tx = t & 15, ty = t >> 4;
  float sR = 0.f, sI = 0.f;
#pragma unroll 8
  for (int k = 0; k < 256; k++) {
    float xr = rp[ty][k][0], xi = rp[ty][k][1];
    float yr = cpT[tx][k][0], yi = cpT[tx][k][1];
    sR = fmaf(xr, yr, sR);
    sR = fmaf(-xi, yi, sR);
    sI = fmaf(xr, yi, sI);
    sI = fmaf(xi, yr, sI);
  }
  float aC, bC;
  if (mode == 0) {
    // semicircle-edge estimate: R = sqrt(2)*||X^2||_F (since ||X||_F = 1);
    // margin 1.75 => sign-safe for lambda_max up to sqrt(3)*1.75*Rhat.
    float Rhat = 1.41421356f * sqrtf(sumsqY[0]);
    float g = 1.0f / (1.75f * Rhat);
    aC = 1.5f * g;
    bC = 0.5f * g * g * g;
  } else if (mode == 1) {
    aC = 2.0f;
    bC = 1.0f;
  } else {
    aC = 1.5f;
    bC = 0.5f;
  }
  int idx = (bi * 16 + ty) * 256 + bj * 16 + tx;
  ZR[idx] = aC * XR[idx] - bC * sR;
  ZI[idx] = aC * XI[idx] - bC * sI;
}

// K7: out = -0.5 * sum(AR.*SR + AI.*SI)   (= -0.5 tr(A S), both Hermitian)
__global__ __launch_bounds__(256) void k_trace(
    const float* __restrict__ AR, const float* __restrict__ AI,
    const float* __restrict__ SR, const float* __restrict__ SI,
    float* __restrict__ out) {
  int t = threadIdx.x;
  float acc = 0.f;
  for (int idx = blockIdx.x * 256 + t; idx < 65536; idx += 64 * 256)
    acc += AR[idx] * SR[idx] + AI[idx] * SI[idx];
#pragma unroll
  for (int o = 32; o > 0; o >>= 1) acc += __shfl_down(acc, o);
  __shared__ float w4[4];
  if ((t & 63) == 0) w4[t >> 6] = acc;
  __syncthreads();
  if (t == 0) atomicAdd(out, -0.5f * (w4[0] + w4[1] + w4[2] + w4[3]));
}

// ---------------------------------------------------------------------------
extern "C" void kernel_launch(void* const* d_in, const int* in_sizes, int n_in,
                              void* d_out, int out_size, void* d_ws,
                              size_t ws_size, hipStream_t stream) {
  const float* x1 = (const float*)d_in[0];
  const float* x0 = (const float*)d_in[1];
  const float* W1 = (const float*)d_in[2];
  const float* b1 = (const float*)d_in[3];
  const float* W2 = (const float*)d_in[4];
  const float* b2 = (const float*)d_in[5];
  const float* W3 = (const float*)d_in[6];
  const float* b3 = (const float*)d_in[7];
  (void)n_in;
  (void)out_size;
  (void)ws_size;

  const int B = in_sizes[0] / 8;       // 65536
  const int total = 2 * B;             // 131072
  const int totalKb = total / 32;      // 4096
  const int kbPer = totalKb / ZSLABS;  // 16

  char* ws = (char*)d_ws;
  size_t off = 0;
  auto carve = [&](size_t bytes) -> void* {
    off = (off + 255) & ~(size_t)255;
    void* p = ws + off;
    off += bytes;
    return p;
  };
  float* hz = (float*)carve((size_t)total * 16 * 4);              // 8.4 MB
  _Float16* Ach = (_Float16*)carve((size_t)totalKb * 16384 * 2);  // 134 MB
  float* P = (float*)carve((size_t)3 * ZSLABS * 2 * 16384 * 4);   // 100.7 MB
  float* scalars = (float*)carve(256);  // [0]=sumsq(A), [1]=sumsqY
  float* AR = (float*)carve(256 * 256 * 4);
  float* AI = (float*)carve(256 * 256 * 4);
  float* XR = (float*)carve(256 * 256 * 4);
  float* XI = (float*)carve(256 * 256 * 4);
  float* YR = (float*)carve(256 * 256 * 4);
  float* YI = (float*)carve(256 * 256 * 4);
  float* ZR = (float*)carve(256 * 256 * 4);
  float* ZI = (float*)carve(256 * 256 * 4);

  k_mlp<<<(total + 255) / 256, 256, 0, stream>>>(
      x1, x0, W1, b1, W2, b2, W3, b3, hz, B, scalars, (float*)d_out);
  k_gen<<<totalKb, 256, 0, stream>>>(hz, Ach);
  k_gemm_t<1><<<dim3(2, ZSLABS), 256, 0, stream>>>(Ach, P, kbPer);
  k_gemm_t<2><<<dim3(1, ZSLABS), 256, 0, stream>>>(Ach, P, kbPer);
  k_reduce<<<dim3(128, 3), 128, 0, stream>>>(P, AR, AI, scalars,
                                             1.0f / (256.0f * (float)B));
  k_scale<<<256, 256, 0, stream>>>(AR, AI, XR, XI, scalars);

  // NS schedule (PROVEN in R3, absmax=0.0 — do not shorten; spectrum has a
  // near-zero eigenvalue cluster that shallow schedules truncate):
  // 1x clamp(1.5-NS, rescaled) + 7x (2x - x^3) + 6x (1.5-NS).
  const int NIT = 14;
  float *cR = XR, *cI = XI, *nR = ZR, *nI = ZI;
  for (int it = 0; it < NIT; it++) {
    int mode = (it == 0) ? 0 : (it <= 7 ? 1 : 2);
    k_csq<<<256, 256, 0, stream>>>(cR, cI, YR, YI, scalars + 1, it == 0);
    k_cupd<<<256, 256, 0, stream>>>(cR, cI, YR, YI, nR, nI, scalars + 1, mode);
    std::swap(cR, nR);
    std::swap(cI, nI);
  }

  k_trace<<<64, 256, 0, stream>>>(AR, AI, cR, cI, (float*)d_out);
}

// Round 6
// 320.829 us; speedup vs baseline: 1.0415x; 1.0415x over previous
//
#include <hip/hip_runtime.h>
#include <cstdint>
#include <cstddef>
#include <utility>

#define PI_F 3.14159265358979323846f

typedef __attribute__((ext_vector_type(8))) _Float16 half8;
typedef __attribute__((ext_vector_type(4))) float f32x4;

struct U4 { unsigned int w[4]; };

static __device__ __forceinline__ unsigned int packhalf2(float c, float s) {
  _Float16 hc = (_Float16)c, hs = (_Float16)s;
  unsigned short uc = __builtin_bit_cast(unsigned short, hc);
  unsigned short us = __builtin_bit_cast(unsigned short, hs);
  return (unsigned int)uc | ((unsigned int)us << 16);
}

static __device__ __forceinline__ void load16_lds(const void* g, void* l) {
  __builtin_amdgcn_global_load_lds(
      (const __attribute__((address_space(1))) unsigned int*)g,
      (__attribute__((address_space(3))) unsigned int*)l, 16, 0, 0);
}

// ---------------------------------------------------------------------------
// K1: MLP for all 2B samples -> hz[sample][16] = {h[0..7], z[0..6], 0}.
// Block 0 thread 0 also zero-inits scalars + out (replaces 2 memset dispatches).
// ---------------------------------------------------------------------------
__global__ __launch_bounds__(256) void k_mlp(
    const float* __restrict__ x1, const float* __restrict__ x0,
    const float* __restrict__ W1, const float* __restrict__ b1,
    const float* __restrict__ W2, const float* __restrict__ b2,
    const float* __restrict__ W3, const float* __restrict__ b3,
    float* __restrict__ hz, int B, float* __restrict__ scalars,
    float* __restrict__ out) {
  int s = blockIdx.x * blockDim.x + threadIdx.x;
  if (blockIdx.x == 0 && threadIdx.x == 0) {
    scalars[0] = 0.f;
    scalars[1] = 0.f;
    out[0] = 0.f;
  }
  if (s >= 2 * B) return;
  const float* xp = (s < B) ? (x1 + (size_t)s * 8) : (x0 + (size_t)(s - B) * 8);
  float x[8];
#pragma unroll
  for (int k = 0; k < 8; k++) x[k] = xp[k];
  float a1[10];
#pragma unroll
  for (int o = 0; o < 10; o++) {
    float v = b1[o];
#pragma unroll
    for (int k = 0; k < 8; k++) v = fmaf(W1[o * 8 + k], x[k], v);
    a1[o] = fmaxf(v, 0.f);
  }
  float a2[10];
#pragma unroll
  for (int o = 0; o < 10; o++) {
    float v = b2[o];
#pragma unroll
    for (int k = 0; k < 10; k++) v = fmaf(W2[o * 10 + k], a1[k], v);
    a2[o] = fmaxf(v, 0.f);
  }
  float h[8];
#pragma unroll
  for (int o = 0; o < 8; o++) {
    float v = b3[o];
#pragma unroll
    for (int k = 0; k < 10; k++) v = fmaf(W3[o * 10 + k], a2[k], v);
    h[o] = v;
  }
  float outv[16];
#pragma unroll
  for (int k = 0; k < 8; k++) outv[k] = h[k];
#pragma unroll
  for (int k = 0; k < 7; k++) outv[8 + k] = (PI_F - h[k]) * (PI_F - h[k + 1]);
  outv[15] = 0.f;
  float4* dst = (float4*)(hz + (size_t)s * 16);
#pragma unroll
  for (int q = 0; q < 4; q++) dst[q] = ((float4*)outv)[q];
}

// ---------------------------------------------------------------------------
// K2: generate fp16 (cos,sin) pairs. A layout: [kb][256 rows][64 halfs],
// rows are 128B; within a row the 16B chunks are XOR-swizzled by (row&7):
//   physical_half(row, logical_half L) = L ^ ((row&7)<<3)
// so the GEMM stages linearly (global_load_lds) and reads conflict-free.
// Gray-code walk over the 5 j-wires: one sign flip per emitted row
// (~6 VALU ops) instead of a 22-op recompute; v_sin/v_cos hardware
// transcendentals with explicit revolution-space range reduction.
// ---------------------------------------------------------------------------
__global__ __launch_bounds__(256) void k_gen(const float* __restrict__ hz,
                                             _Float16* __restrict__ Ach) {
  __shared__ float hzl[32][17];  // padded: conflict-free column reads
  int kb = blockIdx.x, t = threadIdx.x;
  if (t < 128) {
    int smp = t >> 2, q = t & 3;
    const float4 v =
        *(const float4*)(hz + (size_t)(kb * 32 + smp) * 16 + q * 4);
    hzl[smp][q * 4 + 0] = v.x;
    hzl[smp][q * 4 + 1] = v.y;
    hzl[smp][q * 4 + 2] = v.z;
    hzl[smp][q * 4 + 3] = v.w;
  }
  __syncthreads();
  int s = t & 31, oct = t >> 5;  // sample-in-block, basis octet (wires 5-7)
  float h[8], z[7];
#pragma unroll
  for (int k = 0; k < 8; k++) h[k] = hzl[s][k];
#pragma unroll
  for (int k = 0; k < 7; k++) z[k] = hzl[s][8 + k];
  // wire k <-> bit (7-k) of row index i; oct = i&7 -> wires 5,6,7
  float S5 = (oct & 4) ? -1.f : 1.f;
  float S6 = (oct & 2) ? -1.f : 1.f;
  float S7 = (oct & 1) ? -1.f : 1.f;
  float sg[5] = {1.f, 1.f, 1.f, 1.f, 1.f};  // wires 0..4 (vary with j)
  // phi at j=0 (all varying wires +1):
  float phi = h[0] + h[1] + h[2] + h[3] + h[4] + S5 * h[5] + S6 * h[6] +
              S7 * h[7] + z[0] + z[1] + z[2] + z[3] + S5 * z[4] +
              S5 * S6 * z[5] + S6 * S7 * z[6];
  _Float16* dst = Ach + (size_t)kb * 16384;
  const int halfoff = (2 * s) ^ (oct << 3);  // swizzle: row&7 == oct, const

  auto emit = [&](int g, float ph) {
    // theta = ph/2; revolutions = ph/(4*pi); reduce to [0,1) for v_sin/v_cos
    float r = ph * 0.07957747154594767f;
    r = r - floorf(r);
    float sv = __builtin_amdgcn_sinf(r);
    float cv = __builtin_amdgcn_cosf(r);
    *(unsigned int*)(dst + (size_t)(g * 8 + oct) * 64 + halfoff) =
        packhalf2(cv, sv);
  };

  emit(0, phi);
#pragma unroll
  for (int jj = 1; jj < 32; ++jj) {
    const int b = __builtin_ctz(jj);  // compile-time after unroll
    const int w = 4 - b;              // wire whose sign flips
    float nbl = (w == 0) ? 0.f : sg[w - 1] * z[w - 1];
    float nbr = (w == 4) ? S5 * z[4] : sg[w + 1] * z[w];
    phi -= 2.f * sg[w] * (h[w] + nbl + nbr);
    sg[w] = -sg[w];
    emit(jj ^ (jj >> 1), phi);
  }
}

// ---------------------------------------------------------------------------
// K3: triangular split-K MFMA GEMM -> per-slab partial tiles (no atomics).
// Templated on panel count: NP=1 for diagonal tiles (A==B, stage once,
// 32 KiB LDS), NP=2 for the off-diagonal tile (64 KiB LDS).
// diag:  grid (2, ZSLABS), bx=0 -> tile 0 (0,0), bx=1 -> tile 2 (128,128)
// off:   grid (1, ZSLABS), tile 1 (0,128)
// Partials P[(tile*ZSLABS+z)*2 + plane][128*128] f32.
// ---------------------------------------------------------------------------
#define ZSLABS 256

template <int NP>
__global__ __launch_bounds__(256) void k_gemm_t(const _Float16* __restrict__ A,
                                                float* __restrict__ P,
                                                int kbPer) {
  __shared__ _Float16 lds[2][NP][128][64];
  int bx = blockIdx.x, z = blockIdx.y;
  int mbase, nbase, tile;
  if (NP == 1) {
    mbase = bx * 128;
    nbase = bx * 128;
    tile = bx * 2;
  } else {
    mbase = 0;
    nbase = 128;
    tile = 1;
  }
  int t = threadIdx.x, wave = t >> 6, lane = t & 63;
  int wm = wave >> 1, wn = wave & 1;
  unsigned int reMask = (z < ZSLABS / 2) ? 0u : 0x80008000u;
  unsigned int imMask = (z < ZSLABS / 2) ? 0x80000000u : 0x00008000u;
  int kb0 = z * kbPer;

  auto stage = [&](int it, int buf) {
    size_t kb = (size_t)(kb0 + it);
    const char* gA = (const char*)A + kb * 32768 + (size_t)mbase * 128;
    char* lA = (char*)&lds[buf][0][0][0];
#pragma unroll
    for (int q = 0; q < 4; q++) {
      int woff = wave * 4096 + q * 1024;
      load16_lds(gA + woff + lane * 16, lA + woff);
    }
    if (NP == 2) {
      const char* gB = (const char*)A + kb * 32768 + (size_t)nbase * 128;
      char* lB = (char*)&lds[buf][NP - 1][0][0];
#pragma unroll
      for (int q = 0; q < 4; q++) {
        int woff = wave * 4096 + q * 1024;
        load16_lds(gB + woff + lane * 16, lB + woff);
      }
    }
  };

  f32x4 accR[4][4] = {};
  f32x4 accI[4][4] = {};
  stage(0, 0);
  for (int it = 0; it < kbPer; ++it) {
    __syncthreads();  // stage(it) complete; everyone done with buf[(it+1)&1]
    if (it + 1 < kbPer) stage(it + 1, (it + 1) & 1);
    int buf = it & 1;
#pragma unroll
    for (int kk = 0; kk < 2; kk++) {
      int cbase = kk * 4 + (lane >> 4);
      half8 af[4], bfr[4], bfi[4];
#pragma unroll
      for (int fm = 0; fm < 4; fm++) {
        int r = wm * 64 + fm * 16 + (lane & 15);
        af[fm] = *(const half8*)&lds[buf][0][r][(cbase ^ (r & 7)) << 3];
      }
#pragma unroll
      for (int fn = 0; fn < 4; fn++) {
        int r = wn * 64 + fn * 16 + (lane & 15);
        half8 bv = *(const half8*)&lds[buf][NP - 1][r][(cbase ^ (r & 7)) << 3];
        U4 u = __builtin_bit_cast(U4, bv), ur, ui;
#pragma unroll
        for (int q = 0; q < 4; q++) {
          unsigned int xv = u.w[q];
          ur.w[q] = xv ^ reMask;
          ui.w[q] = ((xv << 16) | (xv >> 16)) ^ imMask;
        }
        bfr[fn] = __builtin_bit_cast(half8, ur);
        bfi[fn] = __builtin_bit_cast(half8, ui);
      }
#pragma unroll
      for (int fm = 0; fm < 4; fm++)
#pragma unroll
        for (int fn = 0; fn < 4; fn++) {
          accR[fm][fn] = __builtin_amdgcn_mfma_f32_16x16x32_f16(
              af[fm], bfr[fn], accR[fm][fn], 0, 0, 0);
          accI[fm][fn] = __builtin_amdgcn_mfma_f32_16x16x32_f16(
              af[fm], bfi[fn], accI[fm][fn], 0, 0, 0);
        }
    }
  }
  float* PR = P + ((size_t)(tile * ZSLABS + z) * 2) * 16384;
  float* PI = PR + 16384;
  int r4 = (lane >> 4) * 4, cj = lane & 15;
#pragma unroll
  for (int fm = 0; fm < 4; fm++)
#pragma unroll
    for (int fn = 0; fn < 4; fn++)
#pragma unroll
      for (int r = 0; r < 4; r++) {
        int li = wm * 64 + fm * 16 + r4 + r;
        int lj = wn * 64 + fn * 16 + cj;
        PR[li * 128 + lj] = accR[fm][fn][r];
        PI[li * 128 + lj] = accI[fm][fn][r];
      }
}

// ---------------------------------------------------------------------------
// K4: reduce partials -> Hermitian A (scaled), accumulate ||A||_F^2.
// grid (128 rows, 3 tiles), 128 threads (one per col).
// ---------------------------------------------------------------------------
__global__ __launch_bounds__(128) void k_reduce(const float* __restrict__ P,
                                                float* __restrict__ AR,
                                                float* __restrict__ AI,
                                                float* __restrict__ sumsq,
                                                float scale) {
  int r = blockIdx.x, tile = blockIdx.y, c = threadIdx.x;
  float vR = 0.f, vI = 0.f;
  for (int zz = 0; zz < ZSLABS; zz++) {
    const float* base =
        P + ((size_t)(tile * ZSLABS + zz) * 2) * 16384 + r * 128 + c;
    vR += base[0];
    vI += base[16384];
  }
  vR *= scale;
  vI *= scale;
  int i = (tile == 2) ? 128 + r : r;
  int j = (tile == 0) ? c : 128 + c;
  float ss = 0.f;
  bool diagTile = (tile != 1);
  if (!diagTile || c > r) {
    AR[i * 256 + j] = vR;
    AR[j * 256 + i] = vR;
    AI[i * 256 + j] = vI;
    AI[j * 256 + i] = -vI;
    ss = 2.f * (vR * vR + vI * vI);
  } else if (c == r) {
    AR[i * 256 + j] = vR;
    AI[i * 256 + j] = 0.f;
    ss = vR * vR;
  }
#pragma unroll
  for (int o = 32; o > 0; o >>= 1) ss += __shfl_down(ss, o);
  __shared__ float w2[2];
  if ((c & 63) == 0) w2[c >> 6] = ss;
  __syncthreads();
  if (c == 0) atomicAdd(sumsq, w2[0] + w2[1]);
}

// K5: X = A / ||A||_F
__global__ __launch_bounds__(256) void k_scale(
    const float* __restrict__ AR, const float* __restrict__ AI,
    float* __restrict__ XR, float* __restrict__ XI,
    const float* __restrict__ sumsq) {
  int idx = blockIdx.x * 256 + threadIdx.x;
  float inva = 1.0f / sqrtf(sumsq[0]);
  XR[idx] = AR[idx] * inva;
  XI[idx] = AI[idx] * inva;
}

// ---------------------------------------------------------------------------
// Newton-Schulz complex matmuls, 16x16 tile per block, interleaved re/im LDS.
// ---------------------------------------------------------------------------
__global__ __launch_bounds__(256) void k_csq(
    const float* __restrict__ XR, const float* __restrict__ XI,
    float* __restrict__ YR, float* __restrict__ YI,
    float* __restrict__ sumsqY, int accumNorm) {
  __shared__ float rp[16][256][2];
  __shared__ float cpT[16][258][2];
  int t = threadIdx.x;
  int bi = blockIdx.x >> 4, bj = blockIdx.x & 15;
#pragma unroll
  for (int q = 0; q < 16; q++) {
    rp[q][t][0] = XR[(bi * 16 + q) * 256 + t];
    rp[q][t][1] = XI[(bi * 16 + q) * 256 + t];
  }
  {
    const float* r0 = XR + t * 256 + bj * 16;
    const float* i0 = XI + t * 256 + bj * 16;
#pragma unroll
    for (int c = 0; c < 16; c++) {
      cpT[c][t][0] = r0[c];
      cpT[c][t][1] = i0[c];
    }
  }
  __syncthreads();
  int tx = t & 15, ty = t >> 4;
  float sR = 0.f, sI = 0.f;
#pragma unroll 8
  for (int k = 0; k < 256; k++) {
    float xr = rp[ty][k][0], xi = rp[ty][k][1];
    float yr = cpT[tx][k][0], yi = cpT[tx][k][1];
    sR = fmaf(xr, yr, sR);
    sR = fmaf(-xi, yi, sR);
    sI = fmaf(xr, yi, sI);
    sI = fmaf(xi, yr, sI);
  }
  int i = bi * 16 + ty, j = bj * 16 + tx;
  YR[i * 256 + j] = sR;
  YI[i * 256 + j] = sI;
  if (accumNorm) {
    float v = sR * sR + sI * sI;
#pragma unroll
    for (int o = 32; o > 0; o >>= 1) v += __shfl_down(v, o);
    __shared__ float w4[4];
    if ((t & 63) == 0) w4[t >> 6] = v;
    __syncthreads();
    if (t == 0) atomicAdd(sumsqY, w4[0] + w4[1] + w4[2] + w4[3]);
  }
}

// Z = aC*X - bC*(X@Y).
// mode 0: first iter, 1.5-NS with spectral rescale folded in (clamps to (0,1])
// mode 1: x <- 2x - x^3      (doubling phase)
// mode 2: x <- 1.5x - 0.5x^3 (quadratic polish)
__global__ __launch_bounds__(256) void k_cupd(
    const float* __restrict__ XR, const float* __restrict__ XI,
    const float* __restrict__ YR, const float* __restrict__ YI,
    float* __restrict__ ZR, float* __restrict__ ZI,
    const float* __restrict__ sumsqY, int mode) {
  __shared__ float rp[16][256][2];
  __shared__ float cpT[16][258][2];
  int t = threadIdx.x;
  int bi = blockIdx.x >> 4, bj = blockIdx.x & 15;
#pragma unroll
  for (int q = 0; q < 16; q++) {
    rp[q][t][0] = XR[(bi * 16 + q) * 256 + t];
    rp[q][t][1] = XI[(bi * 16 + q) * 256 + t];
  }
  {
    const float* r0 = YR + t * 256 + bj * 16;
    const float* i0 = YI + t * 256 + bj * 16;
#pragma unroll
    for (int c = 0; c < 16; c++) {
      cpT[c][t][0] = r0[c];
      cpT[c][t][1] = i0[c];
    }
  }
  __syncthreads();
  int tx = t & 15, ty = t >> 4;
  float sR = 0.f, sI = 0.f;
#pragma unroll 8
  for (int k = 0; k < 256; k++) {
    float xr = rp[ty][k][0], xi = rp[ty][k][1];
    float yr = cpT[tx][k][0], yi = cpT[tx][k][1];
    sR = fmaf(xr, yr, sR);
    sR = fmaf(-xi, yi, sR);
    sI = fmaf(xr, yi, sI);
    sI = fmaf(xi, yr, sI);
  }
  float aC, bC;
  if (mode == 0) {
    // semicircle-edge estimate: R = sqrt(2)*||X^2||_F (since ||X||_F = 1);
    // margin 1.75 => sign-safe for lambda_max up to sqrt(3)*1.75*Rhat.
    float Rhat = 1.41421356f * sqrtf(sumsqY[0]);
    float g = 1.0f / (1.75f * Rhat);
    aC = 1.5f * g;
    bC = 0.5f * g * g * g;
  } else if (mode == 1) {
    aC = 2.0f;
    bC = 1.0f;
  } else {
    aC = 1.5f;
    bC = 0.5f;
  }
  int idx = (bi * 16 + ty) * 256 + bj * 16 + tx;
  ZR[idx] = aC * XR[idx] - bC * sR;
  ZI[idx] = aC * XI[idx] - bC * sI;
}

// K7: out = -0.5 * sum(AR.*SR + AI.*SI)   (= -0.5 tr(A S), both Hermitian)
__global__ __launch_bounds__(256) void k_trace(
    const float* __restrict__ AR, const float* __restrict__ AI,
    const float* __restrict__ SR, const float* __restrict__ SI,
    float* __restrict__ out) {
  int t = threadIdx.x;
  float acc = 0.f;
  for (int idx = blockIdx.x * 256 + t; idx < 65536; idx += 64 * 256)
    acc += AR[idx] * SR[idx] + AI[idx] * SI[idx];
#pragma unroll
  for (int o = 32; o > 0; o >>= 1) acc += __shfl_down(acc, o);
  __shared__ float w4[4];
  if ((t & 63) == 0) w4[t >> 6] = acc;
  __syncthreads();
  if (t == 0) atomicAdd(out, -0.5f * (w4[0] + w4[1] + w4[2] + w4[3]));
}

// ---------------------------------------------------------------------------
extern "C" void kernel_launch(void* const* d_in, const int* in_sizes, int n_in,
                              void* d_out, int out_size, void* d_ws,
                              size_t ws_size, hipStream_t stream) {
  const float* x1 = (const float*)d_in[0];
  const float* x0 = (const float*)d_in[1];
  const float* W1 = (const float*)d_in[2];
  const float* b1 = (const float*)d_in[3];
  const float* W2 = (const float*)d_in[4];
  const float* b2 = (const float*)d_in[5];
  const float* W3 = (const float*)d_in[6];
  const float* b3 = (const float*)d_in[7];
  (void)n_in;
  (void)out_size;
  (void)ws_size;

  const int B = in_sizes[0] / 8;       // 65536
  const int total = 2 * B;             // 131072
  const int totalKb = total / 32;      // 4096
  const int kbPer = totalKb / ZSLABS;  // 16

  char* ws = (char*)d_ws;
  size_t off = 0;
  auto carve = [&](size_t bytes) -> void* {
    off = (off + 255) & ~(size_t)255;
    void* p = ws + off;
    off += bytes;
    return p;
  };
  float* hz = (float*)carve((size_t)total * 16 * 4);              // 8.4 MB
  _Float16* Ach = (_Float16*)carve((size_t)totalKb * 16384 * 2);  // 134 MB
  float* P = (float*)carve((size_t)3 * ZSLABS * 2 * 16384 * 4);   // 100.7 MB
  float* scalars = (float*)carve(256);  // [0]=sumsq(A), [1]=sumsqY
  float* AR = (float*)carve(256 * 256 * 4);
  float* AI = (float*)carve(256 * 256 * 4);
  float* XR = (float*)carve(256 * 256 * 4);
  float* XI = (float*)carve(256 * 256 * 4);
  float* YR = (float*)carve(256 * 256 * 4);
  float* YI = (float*)carve(256 * 256 * 4);
  float* ZR = (float*)carve(256 * 256 * 4);
  float* ZI = (float*)carve(256 * 256 * 4);

  k_mlp<<<(total + 255) / 256, 256, 0, stream>>>(
      x1, x0, W1, b1, W2, b2, W3, b3, hz, B, scalars, (float*)d_out);
  k_gen<<<totalKb, 256, 0, stream>>>(hz, Ach);
  k_gemm_t<1><<<dim3(2, ZSLABS), 256, 0, stream>>>(Ach, P, kbPer);
  k_gemm_t<2><<<dim3(1, ZSLABS), 256, 0, stream>>>(Ach, P, kbPer);
  k_reduce<<<dim3(128, 3), 128, 0, stream>>>(P, AR, AI, scalars,
                                             1.0f / (256.0f * (float)B));
  k_scale<<<256, 256, 0, stream>>>(AR, AI, XR, XI, scalars);

  // NS schedule (PROVEN in R3, absmax=0.0 — do not shorten; spectrum has a
  // near-zero eigenvalue cluster that shallow schedules truncate):
  // 1x clamp(1.5-NS, rescaled) + 7x (2x - x^3) + 6x (1.5-NS).
  const int NIT = 14;
  float *cR = XR, *cI = XI, *nR = ZR, *nI = ZI;
  for (int it = 0; it < NIT; it++) {
    int mode = (it == 0) ? 0 : (it <= 7 ? 1 : 2);
    k_csq<<<256, 256, 0, stream>>>(cR, cI, YR, YI, scalars + 1, it == 0);
    k_cupd<<<256, 256, 0, stream>>>(cR, cI, YR, YI, nR, nI, scalars + 1, mode);
    std::swap(cR, nR);
    std::swap(cI, nI);
  }

  k_trace<<<64, 256, 0, stream>>>(AR, AI, cR, cI, (float*)d_out);
}